// Round 1
// baseline (199.722 us; speedup 1.0000x reference)
//
#include <hip/hip_runtime.h>
#include <math.h>

#define BATCH   32768
#define NCH     2048
#define NCH4    (NCH / 4)          // 512 float4 per row
#define CS_BLOCKS 512
#define ROWS_PER_BLOCK (BATCH / CS_BLOCKS)   // 64

// ---------------------------------------------------------------------------
// Pass 1: column sums of x (B x C), fp32. Each block handles 64 rows.
// Thread t owns float4 columns {t, t+256} -> 8 scalar channels exclusively,
// so accumulation is thread-private; one atomicAdd per channel at the end.
// ---------------------------------------------------------------------------
__global__ __launch_bounds__(256) void colsum_kernel(const float* __restrict__ x,
                                                     float* __restrict__ sums) {
    const int t = threadIdx.x;
    const float4* __restrict__ x4 = (const float4*)x;
    size_t base = (size_t)blockIdx.x * ROWS_PER_BLOCK * NCH4 + t;

    float4 a0 = make_float4(0.f, 0.f, 0.f, 0.f);
    float4 a1 = make_float4(0.f, 0.f, 0.f, 0.f);

    #pragma unroll 4
    for (int r = 0; r < ROWS_PER_BLOCK; ++r) {
        float4 v0 = x4[base];
        float4 v1 = x4[base + 256];
        a0.x += v0.x; a0.y += v0.y; a0.z += v0.z; a0.w += v0.w;
        a1.x += v1.x; a1.y += v1.y; a1.z += v1.z; a1.w += v1.w;
        base += NCH4;
    }

    float* s0 = sums + 4 * t;          // channels 4t .. 4t+3
    atomicAdd(s0 + 0, a0.x);
    atomicAdd(s0 + 1, a0.y);
    atomicAdd(s0 + 2, a0.z);
    atomicAdd(s0 + 3, a0.w);
    float* s1 = sums + 1024 + 4 * t;   // channels 1024+4t ..
    atomicAdd(s1 + 0, a1.x);
    atomicAdd(s1 + 1, a1.y);
    atomicAdd(s1 + 2, a1.z);
    atomicAdd(s1 + 3, a1.w);
}

// ---------------------------------------------------------------------------
// Pass 2: per-channel gate g[c] = res[c] + rw * wave[c]
//   phi  = pa[c]*decay + mean[c]
//   res  = (cos(phi - f[c])*0.5 + 0.5)^10
//   wave = sin(pi*p[c])^2 * cos(phi) * wave_scale
// ---------------------------------------------------------------------------
__global__ void gcalc_kernel(const float* __restrict__ sums,
                             const float* __restrict__ freqs,
                             const float* __restrict__ p_decay,
                             const float* __restrict__ w_scale,
                             const float* __restrict__ r_weight,
                             const float* __restrict__ p_acc,
                             const float* __restrict__ spe,
                             float* __restrict__ g) {
    const int c = blockIdx.x * blockDim.x + threadIdx.x;
    if (c >= NCH) return;

    const float phi = p_acc[c] * p_decay[0] + sums[c] * (1.0f / (float)BATCH);

    float t = cosf(phi - freqs[c]) * 0.5f + 0.5f;
    float t2 = t * t;
    float t4 = t2 * t2;
    float t8 = t4 * t4;
    float resonance = t8 * t2;                      // t^10

    float sp = sinf((float)M_PI * spe[c]);
    float wave = sp * sp * cosf(phi) * w_scale[0];

    g[c] = resonance + r_weight[0] * wave;
}

// ---------------------------------------------------------------------------
// Pass 3: out = z * (1 - exp(-|z|)),  z = x * g[c]  (cordic_normalize ~= id)
// ---------------------------------------------------------------------------
__global__ __launch_bounds__(256) void gate_kernel(const float* __restrict__ x,
                                                   const float* __restrict__ g,
                                                   float* __restrict__ out) {
    const float4* __restrict__ x4 = (const float4*)x;
    const float4* __restrict__ g4 = (const float4*)g;
    float4* __restrict__ o4 = (float4*)out;

    const long long n4 = (long long)BATCH * NCH4;               // 16,777,216
    const long long stride = (long long)gridDim.x * blockDim.x;

    for (long long i = (long long)blockIdx.x * blockDim.x + threadIdx.x;
         i < n4; i += stride) {
        float4 xv = x4[i];
        float4 gv = g4[i & (NCH4 - 1)];

        float zx = xv.x * gv.x;
        float zy = xv.y * gv.y;
        float zz = xv.z * gv.z;
        float zw = xv.w * gv.w;

        float4 o;
        o.x = zx * (1.0f - __expf(-fabsf(zx)));
        o.y = zy * (1.0f - __expf(-fabsf(zy)));
        o.z = zz * (1.0f - __expf(-fabsf(zz)));
        o.w = zw * (1.0f - __expf(-fabsf(zw)));
        o4[i] = o;
    }
}

extern "C" void kernel_launch(void* const* d_in, const int* in_sizes, int n_in,
                              void* d_out, int out_size, void* d_ws, size_t ws_size,
                              hipStream_t stream) {
    const float* x     = (const float*)d_in[0];
    const float* freqs = (const float*)d_in[1];
    const float* pdec  = (const float*)d_in[2];
    const float* wscl  = (const float*)d_in[3];
    const float* rwgt  = (const float*)d_in[4];
    const float* pacc  = (const float*)d_in[5];
    const float* spe   = (const float*)d_in[6];
    float* out = (float*)d_out;

    float* sums = (float*)d_ws;            // 2048 floats
    float* g    = sums + NCH;              // 2048 floats

    // zero the column-sum accumulator every call (ws is NOT re-poisoned/zeroed)
    hipMemsetAsync(sums, 0, NCH * sizeof(float), stream);

    colsum_kernel<<<CS_BLOCKS, 256, 0, stream>>>(x, sums);

    gcalc_kernel<<<NCH / 256, 256, 0, stream>>>(sums, freqs, pdec, wscl, rwgt,
                                                pacc, spe, g);

    gate_kernel<<<2048, 256, 0, stream>>>(x, g, out);
}

// Round 3
// 170.018 us; speedup vs baseline: 1.1747x; 1.1747x over previous
//
#include <hip/hip_runtime.h>
#include <math.h>

#define BATCH   32768
#define NCH     2048
#define NCH4    (NCH / 4)          // 512 float4 per row
#define CS_BLOCKS 512
#define ROWS_PER_BLOCK (BATCH / CS_BLOCKS)   // 64

typedef float f32x4 __attribute__((ext_vector_type(4)));

// ---------------------------------------------------------------------------
// Pass 1: per-block partial column sums of x (B x C), fp32.
// Block b handles rows [b*64, b*64+64). Thread t owns float4 columns
// {t, t+256} -> 8 scalar channels, accumulated thread-private.
// Partials land in d_out (gate fully overwrites d_out later, so it's free
// scratch): partial[b*2048 + c].
// ---------------------------------------------------------------------------
__global__ __launch_bounds__(256) void colsum_kernel(const float* __restrict__ x,
                                                     float* __restrict__ partial) {
    const int t = threadIdx.x;
    const f32x4* __restrict__ x4 = (const f32x4*)x;
    size_t base = (size_t)blockIdx.x * ROWS_PER_BLOCK * NCH4 + t;

    f32x4 a0 = {0.f, 0.f, 0.f, 0.f};
    f32x4 a1 = {0.f, 0.f, 0.f, 0.f};

    #pragma unroll 4
    for (int r = 0; r < ROWS_PER_BLOCK; ++r) {
        a0 += x4[base];
        a1 += x4[base + 256];
        base += NCH4;
    }

    f32x4* p4 = (f32x4*)partial;
    p4[(size_t)blockIdx.x * NCH4 + t]       = a0;   // channels 4t..4t+3
    p4[(size_t)blockIdx.x * NCH4 + 256 + t] = a1;   // channels 1024+4t..
}

// ---------------------------------------------------------------------------
// Pass 2: reduce partials and compute per-channel gate g[c] = res + rw*wave
//   phi  = pa[c]*decay + mean[c]
//   res  = (cos(phi - f[c])*0.5 + 0.5)^10
//   wave = sin(pi*p[c])^2 * cos(phi) * wave_scale
// 8 blocks x 256 threads = 2048 threads, one per channel.
// ---------------------------------------------------------------------------
__global__ __launch_bounds__(256) void gcalc_kernel(const float* __restrict__ partial,
                                                    const float* __restrict__ freqs,
                                                    const float* __restrict__ p_decay,
                                                    const float* __restrict__ w_scale,
                                                    const float* __restrict__ r_weight,
                                                    const float* __restrict__ p_acc,
                                                    const float* __restrict__ spe,
                                                    float* __restrict__ g) {
    const int c = blockIdx.x * blockDim.x + threadIdx.x;   // 0..2047

    float s = 0.f;
    #pragma unroll 8
    for (int b = 0; b < CS_BLOCKS; ++b)
        s += partial[(size_t)b * NCH + c];

    const float phi = p_acc[c] * p_decay[0] + s * (1.0f / (float)BATCH);

    float t = cosf(phi - freqs[c]) * 0.5f + 0.5f;
    float t2 = t * t;
    float t4 = t2 * t2;
    float t8 = t4 * t4;
    float resonance = t8 * t2;                      // t^10

    float sp = sinf((float)M_PI * spe[c]);
    float wave = sp * sp * cosf(phi) * w_scale[0];

    g[c] = resonance + r_weight[0] * wave;
}

// ---------------------------------------------------------------------------
// Pass 3: out = z * (1 - exp(-|z|)),  z = x * g[c].
// x should be L3-resident after pass 1 (256 MiB == Infinity Cache size):
//  - NT loads for x (last use; don't allocate on miss)
//  - NT stores for out (don't evict x from L3)
//  - sweep windows in REVERSE so the most-recently-cached lines are read first
// ---------------------------------------------------------------------------
__global__ __launch_bounds__(256) void gate_kernel(const float* __restrict__ x,
                                                   const float* __restrict__ g,
                                                   float* __restrict__ out) {
    const f32x4* __restrict__ x4 = (const f32x4*)x;
    const f32x4* __restrict__ g4 = (const f32x4*)g;
    f32x4* __restrict__ o4 = (f32x4*)out;

    const long long n4 = (long long)BATCH * NCH4;                 // 16,777,216
    const long long stride = (long long)gridDim.x * blockDim.x;   // 524,288
    const int iters = (int)(n4 / stride);                         // 32
    const long long tid = (long long)blockIdx.x * blockDim.x + threadIdx.x;

    for (int j = iters - 1; j >= 0; --j) {
        const long long i = (long long)j * stride + tid;

        f32x4 xv = __builtin_nontemporal_load(&x4[i]);
        f32x4 gv = g4[i & (NCH4 - 1)];

        f32x4 z = xv * gv;

        f32x4 o;
        o.x = z.x * (1.0f - __expf(-fabsf(z.x)));
        o.y = z.y * (1.0f - __expf(-fabsf(z.y)));
        o.z = z.z * (1.0f - __expf(-fabsf(z.z)));
        o.w = z.w * (1.0f - __expf(-fabsf(z.w)));
        __builtin_nontemporal_store(o, &o4[i]);
    }
}

extern "C" void kernel_launch(void* const* d_in, const int* in_sizes, int n_in,
                              void* d_out, int out_size, void* d_ws, size_t ws_size,
                              hipStream_t stream) {
    const float* x     = (const float*)d_in[0];
    const float* freqs = (const float*)d_in[1];
    const float* pdec  = (const float*)d_in[2];
    const float* wscl  = (const float*)d_in[3];
    const float* rwgt  = (const float*)d_in[4];
    const float* pacc  = (const float*)d_in[5];
    const float* spe   = (const float*)d_in[6];
    float* out = (float*)d_out;

    float* partial = out;              // 512*2048 floats = 4 MiB, scratch;
                                       // gate fully overwrites d_out after use
    float* g = (float*)d_ws;           // 2048 floats

    colsum_kernel<<<CS_BLOCKS, 256, 0, stream>>>(x, partial);

    gcalc_kernel<<<NCH / 256, 256, 0, stream>>>(partial, freqs, pdec, wscl, rwgt,
                                                pacc, spe, g);

    gate_kernel<<<2048, 256, 0, stream>>>(x, g, out);
}

// Round 4
// 146.004 us; speedup vs baseline: 1.3679x; 1.1645x over previous
//
#include <hip/hip_runtime.h>
#include <math.h>

#define BATCH   32768
#define NCH     2048
#define NCH4    (NCH / 4)              // 512 f32x4 per row
#define CS_BLOCKS 1024
#define ROWS_PER_BLOCK (BATCH / CS_BLOCKS)   // 32
#define SLICES 16                      // gcalcA slices of the partial reduction

typedef float f32x4 __attribute__((ext_vector_type(4)));

// ---------------------------------------------------------------------------
// Pass 1: per-block partial column sums of x (B x C), fp32.
// Block b handles rows [b*32, b*32+32). Thread t owns f32x4 columns
// {t, t+256} -> 8 scalar channels, thread-private accumulation.
// partial[b*2048 + c] lands in d_out (gate fully overwrites d_out later).
// ---------------------------------------------------------------------------
__global__ __launch_bounds__(256) void colsum_kernel(const float* __restrict__ x,
                                                     float* __restrict__ partial) {
    const int t = threadIdx.x;
    const f32x4* __restrict__ x4 = (const f32x4*)x;
    size_t base = (size_t)blockIdx.x * ROWS_PER_BLOCK * NCH4 + t;

    f32x4 a0 = {0.f, 0.f, 0.f, 0.f};
    f32x4 a1 = {0.f, 0.f, 0.f, 0.f};

    #pragma unroll 4
    for (int r = 0; r < ROWS_PER_BLOCK; ++r) {
        a0 += x4[base];
        a1 += x4[base + 256];
        base += NCH4;
    }

    f32x4* p4 = (f32x4*)partial;
    p4[(size_t)blockIdx.x * NCH4 + t]       = a0;
    p4[(size_t)blockIdx.x * NCH4 + 256 + t] = a1;
}

// ---------------------------------------------------------------------------
// Pass 2a: reduce 1024 partials -> 16 sub-partials per channel.
// 128 blocks x 256 threads = 32768 = 2048 channels x 16 slices.
// ---------------------------------------------------------------------------
__global__ __launch_bounds__(256) void gcalcA_kernel(const float* __restrict__ partial,
                                                     float* __restrict__ sub) {
    const int gid = blockIdx.x * 256 + threadIdx.x;    // 0..32767
    const int c = gid & (NCH - 1);
    const int s = gid >> 11;                            // 0..15
    const int p0 = s * (CS_BLOCKS / SLICES);            // 64 partials per slice

    float acc = 0.f;
    #pragma unroll 8
    for (int p = 0; p < CS_BLOCKS / SLICES; ++p)
        acc += partial[(size_t)(p0 + p) * NCH + c];
    sub[s * NCH + c] = acc;
}

// ---------------------------------------------------------------------------
// Pass 2b: final reduce + per-channel gate g[c] = res + rw*wave
//   phi  = pa[c]*decay + mean[c]
//   res  = (cos(phi - f[c])*0.5 + 0.5)^10
//   wave = sin(pi*p[c])^2 * cos(phi) * wave_scale
// ---------------------------------------------------------------------------
__global__ __launch_bounds__(256) void gcalcB_kernel(const float* __restrict__ sub,
                                                     const float* __restrict__ freqs,
                                                     const float* __restrict__ p_decay,
                                                     const float* __restrict__ w_scale,
                                                     const float* __restrict__ r_weight,
                                                     const float* __restrict__ p_acc,
                                                     const float* __restrict__ spe,
                                                     float* __restrict__ g) {
    const int c = blockIdx.x * 256 + threadIdx.x;       // 0..2047

    float s = 0.f;
    #pragma unroll
    for (int k = 0; k < SLICES; ++k)
        s += sub[k * NCH + c];

    const float phi = p_acc[c] * p_decay[0] + s * (1.0f / (float)BATCH);

    float t = cosf(phi - freqs[c]) * 0.5f + 0.5f;
    float t2 = t * t;
    float t4 = t2 * t2;
    float t8 = t4 * t4;
    float resonance = t8 * t2;                          // t^10

    float sp = sinf((float)M_PI * spe[c]);
    float wave = sp * sp * cosf(phi) * w_scale[0];

    g[c] = resonance + r_weight[0] * wave;
}

// ---------------------------------------------------------------------------
// Pass 3: out = z * (1 - exp(-|z|)),  z = x * g[c].
//  - REGULAR loads for x: re-install x into L3 each replay (out never
//    allocates), so steady-state replays read x from Infinity Cache.
//  - NT stores for out: don't evict x from L3.
//  - 4-deep manual prefetch pipeline: 4 independent loads in flight.
// ---------------------------------------------------------------------------
__global__ __launch_bounds__(256) void gate_kernel(const float* __restrict__ x,
                                                   const float* __restrict__ g,
                                                   float* __restrict__ out) {
    const f32x4* __restrict__ x4 = (const f32x4*)x;
    const f32x4* __restrict__ g4 = (const f32x4*)g;
    f32x4* __restrict__ o4 = (f32x4*)out;

    const int tid = blockIdx.x * 256 + threadIdx.x;     // 0..524287
    const int stride = 2048 * 256;                      // 524288
    // n4 = 16,777,216 -> 32 windows

    const f32x4 gv = g4[tid & (NCH4 - 1)];              // invariant across windows

#define GATEF(v, o)                                                   \
    do {                                                              \
        f32x4 z = (v) * gv;                                           \
        (o).x = z.x * (1.0f - __expf(-fabsf(z.x)));                   \
        (o).y = z.y * (1.0f - __expf(-fabsf(z.y)));                   \
        (o).z = z.z * (1.0f - __expf(-fabsf(z.z)));                   \
        (o).w = z.w * (1.0f - __expf(-fabsf(z.w)));                   \
    } while (0)

    f32x4 v0 = x4[tid + 0 * stride];
    f32x4 v1 = x4[tid + 1 * stride];
    f32x4 v2 = x4[tid + 2 * stride];
    f32x4 v3 = x4[tid + 3 * stride];

    #pragma unroll
    for (int j = 0; j < 28; j += 4) {
        f32x4 n0 = x4[tid + (j + 4) * stride];
        f32x4 n1 = x4[tid + (j + 5) * stride];
        f32x4 n2 = x4[tid + (j + 6) * stride];
        f32x4 n3 = x4[tid + (j + 7) * stride];

        f32x4 o0, o1, o2, o3;
        GATEF(v0, o0); GATEF(v1, o1); GATEF(v2, o2); GATEF(v3, o3);
        __builtin_nontemporal_store(o0, &o4[tid + (j + 0) * stride]);
        __builtin_nontemporal_store(o1, &o4[tid + (j + 1) * stride]);
        __builtin_nontemporal_store(o2, &o4[tid + (j + 2) * stride]);
        __builtin_nontemporal_store(o3, &o4[tid + (j + 3) * stride]);

        v0 = n0; v1 = n1; v2 = n2; v3 = n3;
    }

    f32x4 o0, o1, o2, o3;
    GATEF(v0, o0); GATEF(v1, o1); GATEF(v2, o2); GATEF(v3, o3);
    __builtin_nontemporal_store(o0, &o4[tid + 28 * stride]);
    __builtin_nontemporal_store(o1, &o4[tid + 29 * stride]);
    __builtin_nontemporal_store(o2, &o4[tid + 30 * stride]);
    __builtin_nontemporal_store(o3, &o4[tid + 31 * stride]);
#undef GATEF
}

extern "C" void kernel_launch(void* const* d_in, const int* in_sizes, int n_in,
                              void* d_out, int out_size, void* d_ws, size_t ws_size,
                              hipStream_t stream) {
    const float* x     = (const float*)d_in[0];
    const float* freqs = (const float*)d_in[1];
    const float* pdec  = (const float*)d_in[2];
    const float* wscl  = (const float*)d_in[3];
    const float* rwgt  = (const float*)d_in[4];
    const float* pacc  = (const float*)d_in[5];
    const float* spe   = (const float*)d_in[6];
    float* out = (float*)d_out;

    float* partial = out;               // 1024*2048 floats = 8 MiB scratch in
                                        // d_out; gate fully overwrites later
    float* sub = (float*)d_ws;          // 16*2048 floats
    float* g   = sub + SLICES * NCH;    // 2048 floats

    colsum_kernel<<<CS_BLOCKS, 256, 0, stream>>>(x, partial);

    gcalcA_kernel<<<128, 256, 0, stream>>>(partial, sub);

    gcalcB_kernel<<<NCH / 256, 256, 0, stream>>>(sub, freqs, pdec, wscl, rwgt,
                                                 pacc, spe, g);

    gate_kernel<<<2048, 256, 0, stream>>>(x, g, out);
}